// Round 18
// baseline (239.203 us; speedup 1.0000x reference)
//
#include <hip/hip_runtime.h>
#include <hip/hip_bf16.h>

#define GRIDW 480
#define CELLS_PER_B (GRIDW*GRIDW)       // 230400
#define NCELL (4*CELLS_PER_B)           // 921600
#define NPTS  400000
#define NPB   100000
#define H1D 128
#define H2D 256
#define DD 64
#define SCAN_BLK 900                    // NCELL / 1024
#define GRIDP 1024                      // MLP blocks (4 per CU, LDS ~12KB)
#define NSUB  25000                     // NPTS/16 subtiles (16 sorted pts each)
#define NWAVES (GRIDP*4)                // 4096
#define CNT_NB 1563                     // ceil(NPTS/256)
#define EMIT_NB 3600                    // NCELL/256

typedef unsigned short u16;
typedef __attribute__((ext_vector_type(8))) short bf16x8;
typedef __attribute__((ext_vector_type(4))) float f32x4;
typedef __attribute__((ext_vector_type(4))) unsigned u32x4;
typedef __attribute__((ext_vector_type(2))) unsigned u32x2;

static __device__ __forceinline__ u16 f2bf(float f){
  unsigned u = __float_as_uint(f);
  unsigned r = u + 0x7FFFu + ((u>>16)&1u);
  return (u16)(r>>16);
}
static __device__ __forceinline__ float bf2f(u16 b){
  return __uint_as_float(((unsigned)b) << 16);
}
static __device__ __forceinline__ unsigned cvt_pk_bf16(float lo, float hi){
  unsigned r;
  asm("v_cvt_pk_bf16_f32 %0, %1, %2" : "=v"(r) : "v"(lo), "v"(hi));
  return r;
}

static __device__ __forceinline__ void pack_one(int e, const float* W2, const float* W3,
                                                u16* bp2, u16* bp3){
  if (e < 32768){
    int j = e & 7, c = (e>>3)&15, ko = (e>>7)&15, n = e>>11;
    bp2[e] = f2bf(W2[(ko*8+j)*H2D + n*16 + c]);
  } else {
    int e3 = e - 32768;
    int j = e3 & 7, c = (e3>>3)&15, ko = (e3>>7)&31, n = e3>>12;
    bp3[e3] = f2bf(W3[(ko*8+j)*DD + n*16 + c]);
  }
}

// fused: blocks [0,CNT_NB) count points; blocks [CNT_NB,CNT_NB+192) pack weights
__global__ void k_countpack(const int* __restrict__ xy, unsigned* __restrict__ counts,
                            const float* __restrict__ W2, const float* __restrict__ W3,
                            u16* __restrict__ bp2, u16* __restrict__ bp3){
  int b = blockIdx.x;
  if (b < CNT_NB){
    int p = b*256 + threadIdx.x;
    if (p < NPTS){
      int bb = p / NPB;
      int x = xy[2*p], y = xy[2*p+1];
      atomicAdd(&counts[(bb*GRIDW + x)*GRIDW + y], 1u);
    }
  } else {
    int e = (b - CNT_NB)*256 + threadIdx.x;
    if (e < 49152) pack_one(e, W2, W3, bp2, bp3);
  }
}

__global__ void k_scan2(const unsigned* __restrict__ counts,
                        unsigned* __restrict__ rankF, unsigned* __restrict__ rankC,
                        unsigned* __restrict__ bsumF, unsigned* __restrict__ bsumC){
  __shared__ unsigned shF[256], shC[256];
  int tid = threadIdx.x;
  int base = blockIdx.x*1024 + tid*4;
  unsigned c0=counts[base], c1=counts[base+1], c2=counts[base+2], c3=counts[base+3];
  unsigned f0=c0?1u:0u, f1=c1?1u:0u, f2=c2?1u:0u, f3=c3?1u:0u;
  unsigned sF=f0+f1+f2+f3, sC=c0+c1+c2+c3;
  shF[tid]=sF; shC[tid]=sC; __syncthreads();
  for (int off=1; off<256; off<<=1){
    unsigned tF = (tid>=off) ? shF[tid-off] : 0u;
    unsigned tC = (tid>=off) ? shC[tid-off] : 0u;
    __syncthreads();
    shF[tid] += tF; shC[tid] += tC;
    __syncthreads();
  }
  unsigned eF = shF[tid]-sF, eC = shC[tid]-sC;
  if (tid==255){ bsumF[blockIdx.x]=shF[255]; bsumC[blockIdx.x]=shC[255]; }
  rankF[base]=eF; rankF[base+1]=eF+f0; rankF[base+2]=eF+f0+f1; rankF[base+3]=eF+f0+f1+f2;
  rankC[base]=eC; rankC[base+1]=eC+c0; rankC[base+2]=eC+c0+c1; rankC[base+3]=eC+c0+c1+c2;
}

__global__ void k_scan_bsum2(unsigned* __restrict__ bsumF, unsigned* __restrict__ bsumC){
  __shared__ unsigned shF[1024], shC[1024];
  int tid = threadIdx.x;
  unsigned vF = (tid<SCAN_BLK) ? bsumF[tid] : 0u;
  unsigned vC = (tid<SCAN_BLK) ? bsumC[tid] : 0u;
  shF[tid]=vF; shC[tid]=vC; __syncthreads();
  for (int off=1; off<1024; off<<=1){
    unsigned tF = (tid>=off) ? shF[tid-off] : 0u;
    unsigned tC = (tid>=off) ? shC[tid-off] : 0u;
    __syncthreads();
    shF[tid] += tF; shC[tid] += tC;
    __syncthreads();
  }
  if (tid<SCAN_BLK){ bsumF[tid]=shF[tid]-vF; bsumC[tid]=shC[tid]-vC; }
}

// fused: blocks [0,EMIT_NB) emit unq; blocks [EMIT_NB,EMIT_NB+CNT_NB) scatter.
__global__ void k_emitscatter(
    const unsigned* __restrict__ counts,
    const unsigned* __restrict__ rankF, unsigned* __restrict__ rankC,
    const unsigned* __restrict__ bsumF, const unsigned* __restrict__ bsumC,
    const int* __restrict__ xy,
    unsigned* __restrict__ perm, unsigned* __restrict__ vox,
    float* __restrict__ out){
  int b = blockIdx.x;
  if (b < EMIT_NB){
    int i = b*256 + threadIdx.x;
    if (counts[i]){
      unsigned rF = rankF[i] + bsumF[i>>10];
      int bb = i / CELLS_PER_B;
      int rem = i - bb*CELLS_PER_B;
      int x = rem / GRIDW;
      int y = rem - x*GRIDW;
      float* o = out + 3u*rF;
      o[0]=(float)bb; o[1]=(float)x; o[2]=(float)y;
    }
  } else {
    int p = (b - EMIT_NB)*256 + threadIdx.x;
    if (p < NPTS){
      int bb = p / NPB;
      int x = xy[2*p], y = xy[2*p+1];
      int cell = (bb*GRIDW+x)*GRIDW + y;
      unsigned slot = atomicAdd(&rankC[cell], 1u) + bsumC[cell>>10];
      perm[slot] = (unsigned)p;
      vox[slot]  = rankF[cell] + bsumF[cell>>10];
    }
  }
}

// ---------------------------------------------------------------------------
// Wave-local fused MLP + segmented-max pooling (r16 body, L2-fed weights):
// BOTH wf2 and wf3 fragments read per-use from L2 (bp2/bp3, 96KB resident).
// LDS = cf + 4x2KB private buffers ~ 12KB -> 4 blocks/CU -> 16 waves/CU.
// Zero in-loop barriers.
// ---------------------------------------------------------------------------
__global__ __launch_bounds__(256,2) void k_mlpp(
    const float* __restrict__ pt, const unsigned* __restrict__ perm,
    const unsigned* __restrict__ vox,
    const u16* __restrict__ bp2, const u16* __restrict__ bp3,
    const float* __restrict__ W1, const float* __restrict__ b1,
    const float* __restrict__ b2, const float* __restrict__ b3,
    float* __restrict__ outp,
    unsigned* __restrict__ pvf, unsigned* __restrict__ pvl,
    u16* __restrict__ pmf, u16* __restrict__ pml)
{
  __shared__ __attribute__((aligned(16))) float cf[832];       // W1|b1|b2|b3
  __shared__ __attribute__((aligned(16))) u16 h2p[4][1024];    // 4x2KB wave-private

  const int tid  = threadIdx.x;
  const int lane = tid & 63;
  const int w    = tid >> 6;
  const int g    = lane >> 4;
  const int p    = lane & 15;

  // ---- stage constant vectors into LDS (once) ----
  for (int i = tid; i < 832; i += 256){
    float v;
    if (i < 384) v = W1[i];
    else if (i < 512) v = b1[i-384];
    else if (i < 768) v = b2[i-512];
    else v = b3[i-768];
    cf[i] = v;
  }
  __syncthreads();                       // one-time: cf ready

  u16* hb = h2p[w];                      // this wave's private buffer

  const int wid = blockIdx.x*4 + w;
  int st = wid;

  // ---- prologue prefetch (lanes 0..15 hold the 16 points) ----
  float pf0=0.f, pf1=0.f, pf2=0.f; unsigned vx=0, pmN=0;
  if (lane < 16 && st < NSUB){
    unsigned pm0 = perm[(size_t)st*16 + lane];
    const float* q = pt + 3*(size_t)pm0;
    pf0 = q[0]; pf1 = q[1]; pf2 = q[2];
    vx = vox[(size_t)st*16 + lane];
    if (st + NWAVES < NSUB) pmN = perm[(size_t)(st+NWAVES)*16 + lane];
  }

  for (; st < NSUB; st += NWAVES){
    // issue next-tile prefetch
    float nf0=0.f, nf1=0.f, nf2=0.f; unsigned nvx=0, pmN2=0;
    if (lane < 16 && st + NWAVES < NSUB){
      const float* q = pt + 3*(size_t)pmN;
      nf0 = q[0]; nf1 = q[1]; nf2 = q[2];
      nvx = vox[(size_t)(st+NWAVES)*16 + lane];
      if (st + 2*NWAVES < NSUB) pmN2 = perm[(size_t)(st+2*NWAVES)*16 + lane];
    }

    // broadcast this lane's point coords (point = lane&15)
    float x0 = __shfl(pf0, p, 64);
    float x1 = __shfl(pf1, p, 64);
    float x2 = __shfl(pf2, p, 64);

    // ---- layer 1: compute h1 directly in fragment layout ----
    bf16x8 hf[4];
    #pragma unroll
    for (int t=0;t<4;++t){
      int cb = t*32 + g*8;
      f32x4 wa0 = *(const f32x4*)&cf[cb];
      f32x4 wa1 = *(const f32x4*)&cf[cb+4];
      f32x4 wb0 = *(const f32x4*)&cf[128+cb];
      f32x4 wb1 = *(const f32x4*)&cf[128+cb+4];
      f32x4 wc0 = *(const f32x4*)&cf[256+cb];
      f32x4 wc1 = *(const f32x4*)&cf[256+cb+4];
      f32x4 a0  = *(const f32x4*)&cf[384+cb];
      f32x4 a1  = *(const f32x4*)&cf[384+cb+4];
      #pragma unroll
      for (int i=0;i<4;++i){
        a0[i] = fmaf(x0, wa0[i], a0[i]);
        a1[i] = fmaf(x0, wa1[i], a1[i]);
        a0[i] = fmaf(x1, wb0[i], a0[i]);
        a1[i] = fmaf(x1, wb1[i], a1[i]);
        a0[i] = fmaf(x2, wc0[i], a0[i]);
        a1[i] = fmaf(x2, wc1[i], a1[i]);
        a0[i] = fmaxf(a0[i], 0.f);
        a1[i] = fmaxf(a1[i], 0.f);
      }
      u32x4 ov;
      ov[0] = cvt_pk_bf16(a0[0], a0[1]);
      ov[1] = cvt_pk_bf16(a0[2], a0[3]);
      ov[2] = cvt_pk_bf16(a1[0], a1[1]);
      ov[3] = cvt_pk_bf16(a1[2], a1[3]);
      hf[t] = *(bf16x8*)&ov;
    }

    f32x4 acc3[4];
    #pragma unroll
    for (int a=0;a<4;++a){ acc3[a][0]=0.f; acc3[a][1]=0.f; acc3[a][2]=0.f; acc3[a][3]=0.f; }

    // ---- chunk loop over h2 columns (4 x 64), all wave-local ----
    #pragma unroll
    for (int c=0;c<4;++c){
      f32x4 acc2[4];
      #pragma unroll
      for (int a=0;a<4;++a){ acc2[a][0]=0.f; acc2[a][1]=0.f; acc2[a][2]=0.f; acc2[a][3]=0.f; }
      #pragma unroll
      for (int t=0;t<4;++t){
        #pragma unroll
        for (int nn=0;nn<4;++nn){
          int ngl = c*4 + nn;
          bf16x8 w2f = *(const bf16x8*)(bp2 + (((ngl*16 + t*4 + g)*16) + p)*8);
          acc2[nn] = __builtin_amdgcn_mfma_f32_16x16x32_bf16(w2f, hf[t], acc2[nn], 0, 0, 0);
        }
      }
      // bias + relu -> private h2 chunk (D layout, swizzled)
      #pragma unroll
      for (int nn=0;nn<4;++nn){
        f32x4 b2v = *(const f32x4*)&cf[512 + c*64 + nn*16 + g*4];
        float e0 = fmaxf(acc2[nn][0] + b2v[0], 0.f);
        float e1 = fmaxf(acc2[nn][1] + b2v[1], 0.f);
        float e2 = fmaxf(acc2[nn][2] + b2v[2], 0.f);
        float e3 = fmaxf(acc2[nn][3] + b2v[3], 0.f);
        u32x2 o2; o2[0] = cvt_pk_bf16(e0, e1); o2[1] = cvt_pk_bf16(e2, e3);
        unsigned byte = (unsigned)p*128u + (unsigned)(nn*32 + g*8);
        byte ^= (unsigned)(p&7) << 4;
        *(u32x2*)((char*)hb + byte) = o2;
      }
      // layer-3 partial (reads same-wave private buffer; DS in-order, no barrier)
      #pragma unroll
      for (int t2=0;t2<2;++t2){
        int s = c*2 + t2;
        unsigned hbyte = (unsigned)p*128u + (unsigned)(t2*64 + g*16);
        hbyte ^= (unsigned)(p&7) << 4;
        bf16x8 h2f = *(const bf16x8*)((const char*)hb + hbyte);
        #pragma unroll
        for (int dt=0;dt<4;++dt){
          bf16x8 w3f = *(const bf16x8*)(bp3 + (((dt*32 + s*4 + g)*16) + p)*8);
          acc3[dt] = __builtin_amdgcn_mfma_f32_16x16x32_bf16(w3f, h2f, acc3[dt], 0, 0, 0);
        }
      }
    }

    // ---- epilogue 1: +b3, transpose via private buffer ----
    #pragma unroll
    for (int dt=0;dt<4;++dt){
      f32x4 b3v = *(const f32x4*)&cf[768 + dt*16 + g*4];
      float e0 = acc3[dt][0] + b3v[0];
      float e1 = acc3[dt][1] + b3v[1];
      float e2 = acc3[dt][2] + b3v[2];
      float e3 = acc3[dt][3] + b3v[3];
      u32x2 o2; o2[0] = cvt_pk_bf16(e0, e1); o2[1] = cvt_pk_bf16(e2, e3);
      unsigned byte = (unsigned)p*128u + (unsigned)(dt*32 + g*8);
      byte ^= (unsigned)(p&7) << 4;
      *(u32x2*)((char*)hb + byte) = o2;
    }

    // ---- epilogue 2: segmented max over the 16 sorted rows (lane=channel) ----
    {
      float val[16]; unsigned vid[16];
      #pragma unroll
      for (int r=0;r<16;++r){
        unsigned byte = (unsigned)r*128u + (unsigned)lane*2u;
        byte ^= (unsigned)(r&7) << 4;
        val[r] = bf2f(*(const u16*)((const char*)hb + byte));
        vid[r] = __shfl(vx, r, 64);
      }
      float m = val[0];
      unsigned vprev = vid[0];
      int runstart = 0;
      #pragma unroll
      for (int r=1;r<16;++r){
        if (vid[r] != vprev){
          if (runstart == 0){
            pmf[(size_t)st*64 + lane] = (u16)(__float_as_uint(m)>>16);
            if (lane==0) pvf[st] = vprev;
          } else {
            outp[(size_t)vprev*64 + lane] = m;         // interior run: final
          }
          m = val[r]; runstart = r; vprev = vid[r];
        } else m = fmaxf(m, val[r]);
      }
      pml[(size_t)st*64 + lane] = (u16)(__float_as_uint(m)>>16);
      if (lane==0) pvl[st] = vprev;
      if (runstart == 0){
        pmf[(size_t)st*64 + lane] = (u16)(__float_as_uint(m)>>16);
        if (lane==0) pvf[st] = vprev;
      }
    }
    pf0=nf0; pf1=nf1; pf2=nf2; vx=nvx; pmN=pmN2;
  }
}

// resolve subtile-boundary voxel chains (max is idempotent -> safe overlap)
__global__ __launch_bounds__(256) void k_fixup(
    const unsigned* __restrict__ pvf, const unsigned* __restrict__ pvl,
    const u16* __restrict__ pmf, const u16* __restrict__ pml,
    float* __restrict__ outp){
  int t  = blockIdx.x*4 + (threadIdx.x>>6);
  int ch = threadIdx.x & 63;
  if (t >= NSUB) return;
  unsigned vf = pvf[t], vl = pvl[t];
  if (t == 0 || pvl[t-1] != vf){
    float m = bf2f(pmf[(size_t)t*64 + ch]);
    if (vl == vf){
      m = fmaxf(m, bf2f(pml[(size_t)t*64 + ch]));
      int k = t+1;
      while (k < NSUB && pvf[k] == vf){
        m = fmaxf(m, bf2f(pmf[(size_t)k*64 + ch]));
        if (pvl[k] != vf) break;
        m = fmaxf(m, bf2f(pml[(size_t)k*64 + ch]));
        ++k;
      }
    }
    outp[(size_t)vf*64 + ch] = m;
  }
  if (vl != vf){
    float m = bf2f(pml[(size_t)t*64 + ch]);
    int k = t+1;
    while (k < NSUB && pvf[k] == vl){
      m = fmaxf(m, bf2f(pmf[(size_t)k*64 + ch]));
      if (pvl[k] != vl) break;
      m = fmaxf(m, bf2f(pml[(size_t)k*64 + ch]));
      ++k;
    }
    outp[(size_t)vl*64 + ch] = m;
  }
}

extern "C" void kernel_launch(void* const* d_in, const int* in_sizes, int n_in,
                              void* d_out, int out_size, void* d_ws, size_t ws_size,
                              hipStream_t stream){
  const float* pt = (const float*)d_in[0];
  const int*   xy = (const int*)d_in[1];
  const float* W1 = (const float*)d_in[2];
  const float* b1 = (const float*)d_in[3];
  const float* W2 = (const float*)d_in[4];
  const float* b2 = (const float*)d_in[5];
  const float* W3 = (const float*)d_in[6];
  const float* b3 = (const float*)d_in[7];
  float* out = (float*)d_out;

  int M = out_size / 67;               // out = unq (M*3) ++ pooled (M*64)
  float* outp = out + 3*(size_t)M;

  // workspace layout (u32 units)
  unsigned* counts = (unsigned*)d_ws;
  unsigned* rankF  = counts + NCELL;
  unsigned* rankC  = rankF + NCELL;
  unsigned* bsumF  = rankC + NCELL;
  unsigned* bsumC  = bsumF + 1024;
  unsigned* perm   = bsumC + 1024;
  unsigned* vox    = perm + NPTS;
  unsigned* pvf    = vox + NPTS;
  unsigned* pvl    = pvf + NSUB;
  u16* bp2 = (u16*)(pvl + NSUB);
  u16* bp3 = bp2 + 32768;
  u16* pmf = bp3 + 16384;
  u16* pml = pmf + (size_t)NSUB*64;

  hipMemsetAsync(counts, 0, NCELL*sizeof(unsigned), stream);
  k_countpack  <<<CNT_NB+192, 256, 0, stream>>>(xy, counts, W2, W3, bp2, bp3);
  k_scan2      <<<SCAN_BLK, 256, 0, stream>>>(counts, rankF, rankC, bsumF, bsumC);
  k_scan_bsum2 <<<1, 1024, 0, stream>>>(bsumF, bsumC);
  k_emitscatter<<<EMIT_NB+CNT_NB, 256, 0, stream>>>(counts, rankF, rankC, bsumF, bsumC,
                                                    xy, perm, vox, out);
  k_mlpp       <<<GRIDP, 256, 0, stream>>>(pt, perm, vox, bp2, bp3, W1, b1, b2, b3,
                                           outp, pvf, pvl, pmf, pml);
  k_fixup      <<<NSUB/4, 256, 0, stream>>>(pvf, pvl, pmf, pml, outp);
}

// Round 19
// 145.441 us; speedup vs baseline: 1.6447x; 1.6447x over previous
//
#include <hip/hip_runtime.h>
#include <hip/hip_bf16.h>

#define GRIDW 480
#define CELLS_PER_B (GRIDW*GRIDW)       // 230400
#define NCELL (4*CELLS_PER_B)           // 921600
#define NPTS  400000
#define NPB   100000
#define H1D 128
#define H2D 256
#define DD 64
#define SCAN_BLK 900                    // NCELL / 1024
#define GRIDP 512                       // MLP blocks (2 per CU)
#define NSUB  25000                     // NPTS/16 subtiles (16 sorted pts each)
#define NWAVES (GRIDP*4)
#define CNT_NB 1563                     // ceil(NPTS/256)
#define EMIT_NB 3600                    // NCELL/256

typedef unsigned short u16;
typedef __attribute__((ext_vector_type(8))) short bf16x8;
typedef __attribute__((ext_vector_type(4))) float f32x4;
typedef __attribute__((ext_vector_type(4))) unsigned u32x4;
typedef __attribute__((ext_vector_type(2))) unsigned u32x2;

static __device__ __forceinline__ u16 f2bf(float f){
  unsigned u = __float_as_uint(f);
  unsigned r = u + 0x7FFFu + ((u>>16)&1u);
  return (u16)(r>>16);
}
static __device__ __forceinline__ float bf2f(u16 b){
  return __uint_as_float(((unsigned)b) << 16);
}
static __device__ __forceinline__ unsigned cvt_pk_bf16(float lo, float hi){
  unsigned r;
  asm("v_cvt_pk_bf16_f32 %0, %1, %2" : "=v"(r) : "v"(lo), "v"(hi));
  return r;
}

static __device__ __forceinline__ void pack_one(int e, const float* W2, const float* W3,
                                                u16* bp2, u16* bp3){
  if (e < 32768){
    int j = e & 7, c = (e>>3)&15, ko = (e>>7)&15, n = e>>11;
    bp2[e] = f2bf(W2[(ko*8+j)*H2D + n*16 + c]);
  } else {
    int e3 = e - 32768;
    int j = e3 & 7, c = (e3>>3)&15, ko = (e3>>7)&31, n = e3>>12;
    bp3[e3] = f2bf(W3[(ko*8+j)*DD + n*16 + c]);
  }
}

// fused: blocks [0,CNT_NB) count points; blocks [CNT_NB,CNT_NB+192) pack weights
__global__ void k_countpack(const int* __restrict__ xy, unsigned* __restrict__ counts,
                            const float* __restrict__ W2, const float* __restrict__ W3,
                            u16* __restrict__ bp2, u16* __restrict__ bp3){
  int b = blockIdx.x;
  if (b < CNT_NB){
    int p = b*256 + threadIdx.x;
    if (p < NPTS){
      int bb = p / NPB;
      int x = xy[2*p], y = xy[2*p+1];
      atomicAdd(&counts[(bb*GRIDW + x)*GRIDW + y], 1u);
    }
  } else {
    int e = (b - CNT_NB)*256 + threadIdx.x;
    if (e < 49152) pack_one(e, W2, W3, bp2, bp3);
  }
}

__global__ void k_scan2(const unsigned* __restrict__ counts,
                        unsigned* __restrict__ rankF, unsigned* __restrict__ rankC,
                        unsigned* __restrict__ bsumF, unsigned* __restrict__ bsumC){
  __shared__ unsigned shF[256], shC[256];
  int tid = threadIdx.x;
  int base = blockIdx.x*1024 + tid*4;
  unsigned c0=counts[base], c1=counts[base+1], c2=counts[base+2], c3=counts[base+3];
  unsigned f0=c0?1u:0u, f1=c1?1u:0u, f2=c2?1u:0u, f3=c3?1u:0u;
  unsigned sF=f0+f1+f2+f3, sC=c0+c1+c2+c3;
  shF[tid]=sF; shC[tid]=sC; __syncthreads();
  for (int off=1; off<256; off<<=1){
    unsigned tF = (tid>=off) ? shF[tid-off] : 0u;
    unsigned tC = (tid>=off) ? shC[tid-off] : 0u;
    __syncthreads();
    shF[tid] += tF; shC[tid] += tC;
    __syncthreads();
  }
  unsigned eF = shF[tid]-sF, eC = shC[tid]-sC;
  if (tid==255){ bsumF[blockIdx.x]=shF[255]; bsumC[blockIdx.x]=shC[255]; }
  rankF[base]=eF; rankF[base+1]=eF+f0; rankF[base+2]=eF+f0+f1; rankF[base+3]=eF+f0+f1+f2;
  rankC[base]=eC; rankC[base+1]=eC+c0; rankC[base+2]=eC+c0+c1; rankC[base+3]=eC+c0+c1+c2;
}

__global__ void k_scan_bsum2(unsigned* __restrict__ bsumF, unsigned* __restrict__ bsumC){
  __shared__ unsigned shF[1024], shC[1024];
  int tid = threadIdx.x;
  unsigned vF = (tid<SCAN_BLK) ? bsumF[tid] : 0u;
  unsigned vC = (tid<SCAN_BLK) ? bsumC[tid] : 0u;
  shF[tid]=vF; shC[tid]=vC; __syncthreads();
  for (int off=1; off<1024; off<<=1){
    unsigned tF = (tid>=off) ? shF[tid-off] : 0u;
    unsigned tC = (tid>=off) ? shC[tid-off] : 0u;
    __syncthreads();
    shF[tid] += tF; shC[tid] += tC;
    __syncthreads();
  }
  if (tid<SCAN_BLK){ bsumF[tid]=shF[tid]-vF; bsumC[tid]=shC[tid]-vC; }
}

// fused: blocks [0,EMIT_NB) emit unq; blocks [EMIT_NB,EMIT_NB+CNT_NB) scatter.
__global__ void k_emitscatter(
    const unsigned* __restrict__ counts,
    const unsigned* __restrict__ rankF, unsigned* __restrict__ rankC,
    const unsigned* __restrict__ bsumF, const unsigned* __restrict__ bsumC,
    const int* __restrict__ xy,
    unsigned* __restrict__ perm, unsigned* __restrict__ vox,
    float* __restrict__ out){
  int b = blockIdx.x;
  if (b < EMIT_NB){
    int i = b*256 + threadIdx.x;
    if (counts[i]){
      unsigned rF = rankF[i] + bsumF[i>>10];
      int bb = i / CELLS_PER_B;
      int rem = i - bb*CELLS_PER_B;
      int x = rem / GRIDW;
      int y = rem - x*GRIDW;
      float* o = out + 3u*rF;
      o[0]=(float)bb; o[1]=(float)x; o[2]=(float)y;
    }
  } else {
    int p = (b - EMIT_NB)*256 + threadIdx.x;
    if (p < NPTS){
      int bb = p / NPB;
      int x = xy[2*p], y = xy[2*p+1];
      int cell = (bb*GRIDW+x)*GRIDW + y;
      unsigned slot = atomicAdd(&rankC[cell], 1u) + bsumC[cell>>10];
      perm[slot] = (unsigned)p;
      vox[slot]  = rankF[cell] + bsumF[cell>>10];
    }
  }
}

// ---------------------------------------------------------------------------
// Wave-local fused MLP + segmented-max pooling. ZERO in-loop barriers:
// each wave owns one 16-point subtile end-to-end. h1 computed directly in
// fragment layout (no LDS); h2 through a wave-PRIVATE 2KB LDS buffer
// (same-wave DS ordering, no s_barrier); wf2 from shared read-only LDS;
// wf3 from L2 (bp3, 32KB, cache-resident).  [r14/r16 verified optimum]
// ---------------------------------------------------------------------------
__global__ __launch_bounds__(256,2) void k_mlpp(
    const float* __restrict__ pt, const unsigned* __restrict__ perm,
    const unsigned* __restrict__ vox,
    const u16* __restrict__ bp2, const u16* __restrict__ bp3,
    const float* __restrict__ W1, const float* __restrict__ b1,
    const float* __restrict__ b2, const float* __restrict__ b3,
    float* __restrict__ outp,
    unsigned* __restrict__ pvf, unsigned* __restrict__ pvl,
    u16* __restrict__ pmf, u16* __restrict__ pml)
{
  __shared__ __attribute__((aligned(16))) u16 w2s[32768];      // 64 KB shared RO
  __shared__ __attribute__((aligned(16))) float cf[832];       // W1|b1|b2|b3
  __shared__ __attribute__((aligned(16))) u16 h2p[4][1024];    // 4x2KB wave-private

  const int tid  = threadIdx.x;
  const int lane = tid & 63;
  const int w    = tid >> 6;
  const int g    = lane >> 4;
  const int p    = lane & 15;

  // ---- stage wf2 fragments + constant vectors into LDS (once) ----
  for (int i = tid; i < 4096; i += 256)
    *(u32x4*)((char*)w2s + i*16) = *(const u32x4*)((const char*)bp2 + i*16);
  for (int i = tid; i < 832; i += 256){
    float v;
    if (i < 384) v = W1[i];
    else if (i < 512) v = b1[i-384];
    else if (i < 768) v = b2[i-512];
    else v = b3[i-768];
    cf[i] = v;
  }
  __syncthreads();                       // one-time: w2s/cf ready

  u16* hb = h2p[w];                      // this wave's private buffer

  const int wid = blockIdx.x*4 + w;
  int st = wid;

  // ---- prologue prefetch (lanes 0..15 hold the 16 points) ----
  float pf0=0.f, pf1=0.f, pf2=0.f; unsigned vx=0, pmN=0;
  if (lane < 16 && st < NSUB){
    unsigned pm0 = perm[(size_t)st*16 + lane];
    const float* q = pt + 3*(size_t)pm0;
    pf0 = q[0]; pf1 = q[1]; pf2 = q[2];
    vx = vox[(size_t)st*16 + lane];
    if (st + NWAVES < NSUB) pmN = perm[(size_t)(st+NWAVES)*16 + lane];
  }

  for (; st < NSUB; st += NWAVES){
    // issue next-tile prefetch
    float nf0=0.f, nf1=0.f, nf2=0.f; unsigned nvx=0, pmN2=0;
    if (lane < 16 && st + NWAVES < NSUB){
      const float* q = pt + 3*(size_t)pmN;
      nf0 = q[0]; nf1 = q[1]; nf2 = q[2];
      nvx = vox[(size_t)(st+NWAVES)*16 + lane];
      if (st + 2*NWAVES < NSUB) pmN2 = perm[(size_t)(st+2*NWAVES)*16 + lane];
    }

    // broadcast this lane's point coords (point = lane&15)
    float x0 = __shfl(pf0, p, 64);
    float x1 = __shfl(pf1, p, 64);
    float x2 = __shfl(pf2, p, 64);

    // ---- layer 1: compute h1 directly in fragment layout ----
    // lane holds h1[point=p][ch = t*32 + g*8 + j]
    bf16x8 hf[4];
    #pragma unroll
    for (int t=0;t<4;++t){
      int cb = t*32 + g*8;
      f32x4 wa0 = *(const f32x4*)&cf[cb];
      f32x4 wa1 = *(const f32x4*)&cf[cb+4];
      f32x4 wb0 = *(const f32x4*)&cf[128+cb];
      f32x4 wb1 = *(const f32x4*)&cf[128+cb+4];
      f32x4 wc0 = *(const f32x4*)&cf[256+cb];
      f32x4 wc1 = *(const f32x4*)&cf[256+cb+4];
      f32x4 a0  = *(const f32x4*)&cf[384+cb];
      f32x4 a1  = *(const f32x4*)&cf[384+cb+4];
      #pragma unroll
      for (int i=0;i<4;++i){
        a0[i] = fmaf(x0, wa0[i], a0[i]);
        a1[i] = fmaf(x0, wa1[i], a1[i]);
        a0[i] = fmaf(x1, wb0[i], a0[i]);
        a1[i] = fmaf(x1, wb1[i], a1[i]);
        a0[i] = fmaf(x2, wc0[i], a0[i]);
        a1[i] = fmaf(x2, wc1[i], a1[i]);
        a0[i] = fmaxf(a0[i], 0.f);
        a1[i] = fmaxf(a1[i], 0.f);
      }
      u32x4 ov;
      ov[0] = cvt_pk_bf16(a0[0], a0[1]);
      ov[1] = cvt_pk_bf16(a0[2], a0[3]);
      ov[2] = cvt_pk_bf16(a1[0], a1[1]);
      ov[3] = cvt_pk_bf16(a1[2], a1[3]);
      hf[t] = *(bf16x8*)&ov;
    }

    f32x4 acc3[4];
    #pragma unroll
    for (int a=0;a<4;++a){ acc3[a][0]=0.f; acc3[a][1]=0.f; acc3[a][2]=0.f; acc3[a][3]=0.f; }

    // ---- chunk loop over h2 columns (4 x 64), all wave-local ----
    #pragma unroll
    for (int c=0;c<4;++c){
      f32x4 acc2[4];
      #pragma unroll
      for (int a=0;a<4;++a){ acc2[a][0]=0.f; acc2[a][1]=0.f; acc2[a][2]=0.f; acc2[a][3]=0.f; }
      #pragma unroll
      for (int t=0;t<4;++t){
        #pragma unroll
        for (int nn=0;nn<4;++nn){
          int ngl = c*4 + nn;
          bf16x8 w2f = *(const bf16x8*)((const char*)w2s +
                          (((ngl*16 + t*4 + g)*16) + p)*16);
          acc2[nn] = __builtin_amdgcn_mfma_f32_16x16x32_bf16(w2f, hf[t], acc2[nn], 0, 0, 0);
        }
      }
      // bias + relu -> private h2 chunk (D layout, swizzled)
      #pragma unroll
      for (int nn=0;nn<4;++nn){
        f32x4 b2v = *(const f32x4*)&cf[512 + c*64 + nn*16 + g*4];
        float e0 = fmaxf(acc2[nn][0] + b2v[0], 0.f);
        float e1 = fmaxf(acc2[nn][1] + b2v[1], 0.f);
        float e2 = fmaxf(acc2[nn][2] + b2v[2], 0.f);
        float e3 = fmaxf(acc2[nn][3] + b2v[3], 0.f);
        u32x2 o2; o2[0] = cvt_pk_bf16(e0, e1); o2[1] = cvt_pk_bf16(e2, e3);
        unsigned byte = (unsigned)p*128u + (unsigned)(nn*32 + g*8);
        byte ^= (unsigned)(p&7) << 4;
        *(u32x2*)((char*)hb + byte) = o2;
      }
      // layer-3 partial (reads same-wave private buffer; DS in-order, no barrier)
      #pragma unroll
      for (int t2=0;t2<2;++t2){
        int s = c*2 + t2;
        unsigned hbyte = (unsigned)p*128u + (unsigned)(t2*64 + g*16);
        hbyte ^= (unsigned)(p&7) << 4;
        bf16x8 h2f = *(const bf16x8*)((const char*)hb + hbyte);
        #pragma unroll
        for (int dt=0;dt<4;++dt){
          bf16x8 w3f = *(const bf16x8*)(bp3 + (((dt*32 + s*4 + g)*16) + p)*8);
          acc3[dt] = __builtin_amdgcn_mfma_f32_16x16x32_bf16(w3f, h2f, acc3[dt], 0, 0, 0);
        }
      }
    }

    // ---- epilogue 1: +b3, transpose via private buffer ----
    #pragma unroll
    for (int dt=0;dt<4;++dt){
      f32x4 b3v = *(const f32x4*)&cf[768 + dt*16 + g*4];
      float e0 = acc3[dt][0] + b3v[0];
      float e1 = acc3[dt][1] + b3v[1];
      float e2 = acc3[dt][2] + b3v[2];
      float e3 = acc3[dt][3] + b3v[3];
      u32x2 o2; o2[0] = cvt_pk_bf16(e0, e1); o2[1] = cvt_pk_bf16(e2, e3);
      unsigned byte = (unsigned)p*128u + (unsigned)(dt*32 + g*8);
      byte ^= (unsigned)(p&7) << 4;
      *(u32x2*)((char*)hb + byte) = o2;
    }

    // ---- epilogue 2: segmented max over the 16 sorted rows (lane=channel) ----
    {
      float val[16]; unsigned vid[16];
      #pragma unroll
      for (int r=0;r<16;++r){
        unsigned byte = (unsigned)r*128u + (unsigned)lane*2u;
        byte ^= (unsigned)(r&7) << 4;
        val[r] = bf2f(*(const u16*)((const char*)hb + byte));
        vid[r] = __shfl(vx, r, 64);
      }
      float m = val[0];
      unsigned vprev = vid[0];
      int runstart = 0;
      #pragma unroll
      for (int r=1;r<16;++r){
        if (vid[r] != vprev){
          if (runstart == 0){
            pmf[(size_t)st*64 + lane] = (u16)(__float_as_uint(m)>>16);
            if (lane==0) pvf[st] = vprev;
          } else {
            outp[(size_t)vprev*64 + lane] = m;         // interior run: final
          }
          m = val[r]; runstart = r; vprev = vid[r];
        } else m = fmaxf(m, val[r]);
      }
      pml[(size_t)st*64 + lane] = (u16)(__float_as_uint(m)>>16);
      if (lane==0) pvl[st] = vprev;
      if (runstart == 0){
        pmf[(size_t)st*64 + lane] = (u16)(__float_as_uint(m)>>16);
        if (lane==0) pvf[st] = vprev;
      }
    }
    pf0=nf0; pf1=nf1; pf2=nf2; vx=nvx; pmN=pmN2;
  }
}

// resolve subtile-boundary voxel chains (max is idempotent -> safe overlap)
__global__ __launch_bounds__(256) void k_fixup(
    const unsigned* __restrict__ pvf, const unsigned* __restrict__ pvl,
    const u16* __restrict__ pmf, const u16* __restrict__ pml,
    float* __restrict__ outp){
  int t  = blockIdx.x*4 + (threadIdx.x>>6);
  int ch = threadIdx.x & 63;
  if (t >= NSUB) return;
  unsigned vf = pvf[t], vl = pvl[t];
  if (t == 0 || pvl[t-1] != vf){
    float m = bf2f(pmf[(size_t)t*64 + ch]);
    if (vl == vf){
      m = fmaxf(m, bf2f(pml[(size_t)t*64 + ch]));
      int k = t+1;
      while (k < NSUB && pvf[k] == vf){
        m = fmaxf(m, bf2f(pmf[(size_t)k*64 + ch]));
        if (pvl[k] != vf) break;
        m = fmaxf(m, bf2f(pml[(size_t)k*64 + ch]));
        ++k;
      }
    }
    outp[(size_t)vf*64 + ch] = m;
  }
  if (vl != vf){
    float m = bf2f(pml[(size_t)t*64 + ch]);
    int k = t+1;
    while (k < NSUB && pvf[k] == vl){
      m = fmaxf(m, bf2f(pmf[(size_t)k*64 + ch]));
      if (pvl[k] != vl) break;
      m = fmaxf(m, bf2f(pml[(size_t)k*64 + ch]));
      ++k;
    }
    outp[(size_t)vl*64 + ch] = m;
  }
}

extern "C" void kernel_launch(void* const* d_in, const int* in_sizes, int n_in,
                              void* d_out, int out_size, void* d_ws, size_t ws_size,
                              hipStream_t stream){
  const float* pt = (const float*)d_in[0];
  const int*   xy = (const int*)d_in[1];
  const float* W1 = (const float*)d_in[2];
  const float* b1 = (const float*)d_in[3];
  const float* W2 = (const float*)d_in[4];
  const float* b2 = (const float*)d_in[5];
  const float* W3 = (const float*)d_in[6];
  const float* b3 = (const float*)d_in[7];
  float* out = (float*)d_out;

  int M = out_size / 67;               // out = unq (M*3) ++ pooled (M*64)
  float* outp = out + 3*(size_t)M;

  // workspace layout (u32 units)
  unsigned* counts = (unsigned*)d_ws;
  unsigned* rankF  = counts + NCELL;
  unsigned* rankC  = rankF + NCELL;
  unsigned* bsumF  = rankC + NCELL;
  unsigned* bsumC  = bsumF + 1024;
  unsigned* perm   = bsumC + 1024;
  unsigned* vox    = perm + NPTS;
  unsigned* pvf    = vox + NPTS;
  unsigned* pvl    = pvf + NSUB;
  u16* bp2 = (u16*)(pvl + NSUB);
  u16* bp3 = bp2 + 32768;
  u16* pmf = bp3 + 16384;
  u16* pml = pmf + (size_t)NSUB*64;

  hipMemsetAsync(counts, 0, NCELL*sizeof(unsigned), stream);
  k_countpack  <<<CNT_NB+192, 256, 0, stream>>>(xy, counts, W2, W3, bp2, bp3);
  k_scan2      <<<SCAN_BLK, 256, 0, stream>>>(counts, rankF, rankC, bsumF, bsumC);
  k_scan_bsum2 <<<1, 1024, 0, stream>>>(bsumF, bsumC);
  k_emitscatter<<<EMIT_NB+CNT_NB, 256, 0, stream>>>(counts, rankF, rankC, bsumF, bsumC,
                                                    xy, perm, vox, out);
  k_mlpp       <<<GRIDP, 256, 0, stream>>>(pt, perm, vox, bp2, bp3, W1, b1, b2, b3,
                                           outp, pvf, pvl, pmf, pml);
  k_fixup      <<<NSUB/4, 256, 0, stream>>>(pvf, pvl, pmf, pml, outp);
}